// Round 6
// baseline (340.555 us; speedup 1.0000x reference)
//
#include <hip/hip_runtime.h>

#define N_NODES 100000
#define N_EDGES 1600000
#define N_GRAPHS 512
#define NBUCK 391          // ceil(N_NODES / 256)
#define EPB 8192           // edges per block for scatter
#define NB_SCAT ((N_EDGES + EPB - 1) / EPB)   // 196
#define CAPB 4864          // slot capacity per bucket (mean 4092, +12 sigma)
#define CAP 5120           // LDS staging capacity in bucket_fine

#define CONV_BLKS 6250     // N_NODES*16/256
#define PACK_BLKS 24       // 96 slices / 4 per block
#define PREP_BLKS (CONV_BLKS + NB_SCAT + PACK_BLKS)

typedef _Float16 half8 __attribute__((ext_vector_type(8)));
typedef float floatx4 __attribute__((ext_vector_type(4)));

union U16 { uint4 u; half8 h; };

// ---------- merged prep: convert_f16 || bucket_scatter || pack_w ----------
__global__ __launch_bounds__(256) void prep_kernel(const float4* __restrict__ X4,
                                                   uint4* __restrict__ Xh,
                                                   const int* __restrict__ src,
                                                   const int* __restrict__ dst,
                                                   int* __restrict__ gcur,
                                                   unsigned* __restrict__ pairs,
                                                   const float* __restrict__ W0,
                                                   const float* __restrict__ W1,
                                                   const float* __restrict__ W2,
                                                   uint4* __restrict__ Bp) {
    int bid = blockIdx.x;
    int tid = threadIdx.x;
    if (bid < CONV_BLKS) {
        // fp32 -> fp16 convert
        int t = bid * 256 + tid;
        float4 a = X4[t * 2], b = X4[t * 2 + 1];
        U16 o;
        o.h[0] = (_Float16)a.x; o.h[1] = (_Float16)a.y;
        o.h[2] = (_Float16)a.z; o.h[3] = (_Float16)a.w;
        o.h[4] = (_Float16)b.x; o.h[5] = (_Float16)b.y;
        o.h[6] = (_Float16)b.z; o.h[7] = (_Float16)b.w;
        Xh[t] = o.u;
    } else if (bid < CONV_BLKS + NB_SCAT) {
        // bucket scatter: pairs entry = src | (dst&255)<<17
        __shared__ int cnt[NBUCK];
        __shared__ int base[NBUCK];
        int sb = bid - CONV_BLKS;
        for (int i = tid; i < NBUCK; i += 256) cnt[i] = 0;
        __syncthreads();
        int e0 = sb * EPB, e1 = min(e0 + EPB, N_EDGES);
        for (int e = e0 + tid; e < e1; e += 256) atomicAdd(&cnt[dst[e] >> 8], 1);
        __syncthreads();
        for (int i = tid; i < NBUCK; i += 256) {
            int v = cnt[i];
            base[i] = i * CAPB + (v ? atomicAdd(&gcur[i], v) : 0);
            cnt[i] = 0;
        }
        __syncthreads();
        for (int e = e0 + tid; e < e1; e += 256) {
            int d = dst[e], b = d >> 8;
            int r = atomicAdd(&cnt[b], 1);
            pairs[base[b] + r] = (unsigned)src[e] | ((unsigned)(d & 255) << 17);
        }
    } else {
        // pack W into MFMA B-fragment order:
        // Bp[layer*2048 + (c*8+f)*64 + l] = W[(f*16+(l&15))*128 + c*32 + (l>>4)*8 + j]
        int slice = (bid - CONV_BLKS - NB_SCAT) * 4 + (tid >> 6);   // 0..95
        int l = tid & 63;
        int layer = slice >> 5;
        int r = slice & 31;
        int c = r >> 3, f = r & 7;
        const float* W = (layer == 0) ? W0 : (layer == 1) ? W1 : W2;
        int col = f * 16 + (l & 15);
        int k0 = c * 32 + (l >> 4) * 8;
        U16 o;
        #pragma unroll
        for (int j = 0; j < 8; ++j) o.h[j] = (_Float16)W[col * 128 + k0 + j];
        Bp[layer * 2048 + (c * 8 + f) * 64 + l] = o.u;
    }
}

// ---------- scan: counts in gcur -> boff prefix; off[N]=E ----------
__global__ __launch_bounds__(512) void bucket_scan(const int* __restrict__ gcur,
                                                   int* __restrict__ boff,
                                                   int* __restrict__ off) {
    __shared__ int ws[8];
    int tid = threadIdx.x;
    int v = (tid < NBUCK) ? gcur[tid] : 0;
    int lane = tid & 63, w = tid >> 6;
    int incl = v;
    #pragma unroll
    for (int s = 1; s < 64; s <<= 1) { int y = __shfl_up(incl, s, 64); if (lane >= s) incl += y; }
    if (lane == 63) ws[w] = incl;
    __syncthreads();
    if (tid < 8) {
        int t = ws[tid];
        #pragma unroll
        for (int s = 1; s < 8; s <<= 1) { int y = __shfl_up(t, s, 64); if (tid >= s) t += y; }
        ws[tid] = t;
    }
    __syncthreads();
    int excl = (w ? ws[w - 1] : 0) + incl - v;
    if (tid < NBUCK) boff[tid] = excl;
    if (tid == NBUCK - 1) boff[NBUCK] = excl + v;
    if (tid == 0) off[N_NODES] = N_EDGES;
}

// ---------- fine sort within bucket -> off[] + srclist[] ----------
__global__ __launch_bounds__(256) void bucket_fine(const unsigned* __restrict__ pairs,
                                                   const int* __restrict__ boff,
                                                   int* __restrict__ off,
                                                   int* __restrict__ srclist) {
    __shared__ int ncnt[256];
    __shared__ int ws[4];
    __shared__ int stage[CAP];
    int tid = threadIdx.x, b = blockIdx.x;
    int eLo = boff[b], m = boff[b + 1] - eLo;
    int sb = b * CAPB;
    ncnt[tid] = 0;
    __syncthreads();
    for (int t = tid; t < m; t += 256) {
        unsigned p = pairs[sb + t];
        atomicAdd(&ncnt[(p >> 17) & 255], 1);
    }
    __syncthreads();
    int v = ncnt[tid];
    int lane = tid & 63, w = tid >> 6;
    int incl = v;
    #pragma unroll
    for (int s = 1; s < 64; s <<= 1) { int y = __shfl_up(incl, s, 64); if (lane >= s) incl += y; }
    if (lane == 63) ws[w] = incl;
    __syncthreads();
    if (tid < 4) {
        int t = ws[tid];
        #pragma unroll
        for (int s = 1; s < 4; s <<= 1) { int y = __shfl_up(t, s, 64); if (tid >= s) t += y; }
        ws[tid] = t;
    }
    __syncthreads();
    int excl = (w ? ws[w - 1] : 0) + incl - v;
    int n = (b << 8) + tid;
    if (n < N_NODES) off[n] = eLo + excl;
    __syncthreads();
    ncnt[tid] = excl;   // cursor
    __syncthreads();
    for (int t = tid; t < m; t += 256) {
        unsigned p = pairs[sb + t];
        int r = atomicAdd(&ncnt[(p >> 17) & 255], 1);
        int s = (int)(p & 0x1FFFFu);
        if (r < CAP) stage[r] = s;
        else srclist[eLo + r] = s;
    }
    __syncthreads();
    int lim = m < CAP ? m : CAP;
    for (int t = tid; t < lim; t += 256) srclist[eLo + t] = stage[t];
}

// ---------- pull aggregation (fp16 gather + pk accum), no LDS ----------
__global__ __launch_bounds__(256) void agg_f16(const uint4* __restrict__ Xh,
                                               uint4* __restrict__ Ah,
                                               const int* __restrict__ off,
                                               const int* __restrict__ srclist) {
    int t = blockIdx.x * 256 + threadIdx.x;
    int n = t >> 4, c = t & 15;
    if (n >= N_NODES) return;
    int j0 = off[n], j1 = off[n + 1];
    U16 acc; acc.u = Xh[(size_t)n * 16 + c];   // own row (GIN eps=0)
    half8 a = acc.h;
    int j = j0;
    for (; j + 8 <= j1; j += 8) {
        int s0 = srclist[j],     s1 = srclist[j + 1], s2 = srclist[j + 2], s3 = srclist[j + 3];
        int s4 = srclist[j + 4], s5 = srclist[j + 5], s6 = srclist[j + 6], s7 = srclist[j + 7];
        U16 v0, v1, v2, v3, v4, v5, v6, v7;
        v0.u = Xh[(size_t)s0 * 16 + c];
        v1.u = Xh[(size_t)s1 * 16 + c];
        v2.u = Xh[(size_t)s2 * 16 + c];
        v3.u = Xh[(size_t)s3 * 16 + c];
        v4.u = Xh[(size_t)s4 * 16 + c];
        v5.u = Xh[(size_t)s5 * 16 + c];
        v6.u = Xh[(size_t)s6 * 16 + c];
        v7.u = Xh[(size_t)s7 * 16 + c];
        a += v0.h; a += v1.h; a += v2.h; a += v3.h;
        a += v4.h; a += v5.h; a += v6.h; a += v7.h;
    }
    for (; j < j1; ++j) {
        U16 v; v.u = Xh[(size_t)srclist[j] * 16 + c];
        a += v.h;
    }
    U16 o; o.h = a;
    Ah[(size_t)n * 16 + c] = o.u;
}

// ---------- MFMA GEMM: H[n] = act(A[n] @ W.T + b), A-frags from global, no LDS ----------
__global__ __launch_bounds__(256) void gemm_mfma(const _Float16* __restrict__ Ah,
                                                 const uint4* __restrict__ Bp,
                                                 const float* __restrict__ bias,
                                                 _Float16* __restrict__ H, int doRelu) {
    int tid = threadIdx.x;
    int wid = tid >> 6, lane = tid & 63;
    int nbase = blockIdx.x * 128 + wid * 32;
    int lrow = lane & 15;
    int lk = (lane >> 4) * 8;
    int row0 = min(nbase + lrow, N_NODES - 1);
    int row1 = min(nbase + 16 + lrow, N_NODES - 1);

    floatx4 acc[2][8];
    #pragma unroll
    for (int r = 0; r < 2; ++r)
        #pragma unroll
        for (int f = 0; f < 8; ++f) acc[r][f] = (floatx4)0.f;

    #pragma unroll
    for (int c = 0; c < 4; ++c) {
        U16 a0, a1;
        a0.u = *(const uint4*)(Ah + (size_t)row0 * 128 + c * 32 + lk);
        a1.u = *(const uint4*)(Ah + (size_t)row1 * 128 + c * 32 + lk);
        #pragma unroll
        for (int f = 0; f < 8; ++f) {
            U16 b; b.u = Bp[(c * 8 + f) * 64 + lane];
            acc[0][f] = __builtin_amdgcn_mfma_f32_16x16x32_f16(a0.h, b.h, acc[0][f], 0, 0, 0);
            acc[1][f] = __builtin_amdgcn_mfma_f32_16x16x32_f16(a1.h, b.h, acc[1][f], 0, 0, 0);
        }
    }

    int colb = lane & 15;
    int rq = (lane >> 4) * 4;
    #pragma unroll
    for (int f = 0; f < 8; ++f) {
        float bv = bias[f * 16 + colb];
        #pragma unroll
        for (int r = 0; r < 2; ++r) {
            #pragma unroll
            for (int q = 0; q < 4; ++q) {
                int row = nbase + r * 16 + rq + q;
                if (row < N_NODES) {
                    float v = acc[r][f][q] + bv;
                    if (doRelu) v = fmaxf(v, 0.f);
                    H[(size_t)row * 128 + f * 16 + colb] = (_Float16)v;
                }
            }
        }
    }
}

// ---------- pooling + classifier ----------
__device__ __forceinline__ int lower_bound_i(const int* a, int n, int val) {
    int lo = 0, hi = n;
    while (lo < hi) {
        int mid = (lo + hi) >> 1;
        if (a[mid] < val) lo = mid + 1; else hi = mid;
    }
    return lo;
}

__global__ __launch_bounds__(256) void pool_kernel(const uint4* __restrict__ Hh,
                                                   const int* __restrict__ batch,
                                                   const float* __restrict__ Wg,
                                                   const float* __restrict__ bg,
                                                   float* __restrict__ out) {
    __shared__ float p[16 * 128];
    __shared__ float pooled[128];
    int g = blockIdx.x, tid = threadIdx.x;
    int c = tid & 15, r = tid >> 4;
    int lo = lower_bound_i(batch, N_NODES, g);
    int hi = lower_bound_i(batch, N_NODES, g + 1);
    float acc[8] = {0, 0, 0, 0, 0, 0, 0, 0};
    for (int i = lo + r; i < hi; i += 16) {
        U16 v; v.u = Hh[(size_t)i * 16 + c];
        #pragma unroll
        for (int k = 0; k < 8; ++k) acc[k] += (float)v.h[k];
    }
    #pragma unroll
    for (int k = 0; k < 8; ++k) p[r * 128 + c * 8 + k] = acc[k];
    __syncthreads();
    if (tid < 128) {
        float s = 0.f;
        #pragma unroll
        for (int q = 0; q < 16; ++q) s += p[q * 128 + tid];
        pooled[tid] = s / fmaxf((float)(hi - lo), 1.0f);
    }
    __syncthreads();
    if (tid < 10) {
        float s = bg[tid];
        #pragma unroll 4
        for (int k = 0; k < 128; ++k) s += pooled[k] * Wg[tid * 128 + k];
        out[g * 10 + tid] = s;
    }
}

// ---------- launch ----------
extern "C" void kernel_launch(void* const* d_in, const int* in_sizes, int n_in,
                              void* d_out, int out_size, void* d_ws, size_t ws_size,
                              hipStream_t stream) {
    const float* x   = (const float*)d_in[0];
    const int*   ei  = (const int*)d_in[1];
    const int*   bat = (const int*)d_in[2];
    const float* W0  = (const float*)d_in[3];
    const float* b0  = (const float*)d_in[4];
    const float* W1  = (const float*)d_in[5];
    const float* b1  = (const float*)d_in[6];
    const float* W2  = (const float*)d_in[7];
    const float* b2  = (const float*)d_in[8];
    const float* Wg  = (const float*)d_in[9];
    const float* bg  = (const float*)d_in[10];
    float* out = (float*)d_out;

    const int* src = ei;
    const int* dst = ei + N_EDGES;

    char* w = (char*)d_ws;
    _Float16* Ah    = (_Float16*)(w);               // 25.6 MB fp16 A (aliases pairs)
    unsigned* pairs = (unsigned*)(w);               // 7.6 MB, dead before first agg
    _Float16* P0    = (_Float16*)(w + 25600000);    // X mirror; later H2
    _Float16* P1    = (_Float16*)(w + 51200000);    // H0
    _Float16* P2    = (_Float16*)(w + 76800000);    // H1
    int*    srclist = (int*)(w + 102400000);        // 6.4 MB
    int*    off     = (int*)(w + 108800000);        // 400,016 B
    uint4*  Bp      = (uint4*)(w + 109300000);      // 98,304 B
    int*    gcur    = (int*)(w + 109450000);        // NBUCK ints
    int*    boff    = gcur + NBUCK + 1;             // NBUCK+1 ints

    hipMemsetAsync(gcur, 0, NBUCK * sizeof(int), stream);

    // merged prep: convert || scatter || pack_w
    prep_kernel<<<PREP_BLKS, 256, 0, stream>>>((const float4*)x, (uint4*)P0,
                                               src, dst, gcur, pairs,
                                               W0, W1, W2, Bp);
    bucket_scan<<<1, 512, 0, stream>>>(gcur, boff, off);
    bucket_fine<<<NBUCK, 256, 0, stream>>>(pairs, boff, off, srclist);

    int aggGrid  = (N_NODES * 16 + 255) / 256;   // 6250
    int gemmGrid = (N_NODES + 127) / 128;        // 782

    // layer 0: P0 -> A -> P1
    agg_f16<<<aggGrid, 256, 0, stream>>>((const uint4*)P0, (uint4*)Ah, off, srclist);
    gemm_mfma<<<gemmGrid, 256, 0, stream>>>(Ah, Bp, b0, P1, 1);
    // layer 1: P1 -> A -> P2
    agg_f16<<<aggGrid, 256, 0, stream>>>((const uint4*)P1, (uint4*)Ah, off, srclist);
    gemm_mfma<<<gemmGrid, 256, 0, stream>>>(Ah, Bp + 2048, b1, P2, 1);
    // layer 2: P2 -> A -> P0
    agg_f16<<<aggGrid, 256, 0, stream>>>((const uint4*)P2, (uint4*)Ah, off, srclist);
    gemm_mfma<<<gemmGrid, 256, 0, stream>>>(Ah, Bp + 4096, b2, P0, 0);

    // pool + classifier
    pool_kernel<<<N_GRAPHS, 256, 0, stream>>>((const uint4*)P0, bat, Wg, bg, out);
}

// Round 7
// 340.107 us; speedup vs baseline: 1.0013x; 1.0013x over previous
//
#include <hip/hip_runtime.h>

#define N_NODES 100000
#define N_EDGES 1600000
#define N_GRAPHS 512
#define NBUCK 391          // ceil(N_NODES / 256)
#define EPB 8192           // edges per block for scatter
#define NB_SCAT ((N_EDGES + EPB - 1) / EPB)   // 196
#define CAPB 4864          // slot capacity per bucket (mean 4092, +12 sigma)
#define CAP 5120           // LDS staging capacity in bucket_fine

typedef _Float16 half8 __attribute__((ext_vector_type(8)));
typedef float floatx4 __attribute__((ext_vector_type(4)));

union U16 { uint4 u; half8 h; };

// ---------- fp32 -> fp16 convert ----------
__global__ __launch_bounds__(256) void convert_f16(const float4* __restrict__ X4,
                                                   uint4* __restrict__ Xh) {
    int t = blockIdx.x * 256 + threadIdx.x;
    if (t >= N_NODES * 16) return;
    float4 a = X4[t * 2], b = X4[t * 2 + 1];
    U16 o;
    o.h[0] = (_Float16)a.x; o.h[1] = (_Float16)a.y;
    o.h[2] = (_Float16)a.z; o.h[3] = (_Float16)a.w;
    o.h[4] = (_Float16)b.x; o.h[5] = (_Float16)b.y;
    o.h[6] = (_Float16)b.z; o.h[7] = (_Float16)b.w;
    Xh[t] = o.u;
}

// ---------- bucket scatter: pairs entry = src | (dst&255)<<17 ----------
__global__ __launch_bounds__(256) void bucket_scatter(const int* __restrict__ src,
                                                      const int* __restrict__ dst,
                                                      int* __restrict__ gcur,
                                                      unsigned* __restrict__ pairs) {
    __shared__ int cnt[NBUCK];
    __shared__ int base[NBUCK];
    int tid = threadIdx.x;
    for (int i = tid; i < NBUCK; i += 256) cnt[i] = 0;
    __syncthreads();
    int e0 = blockIdx.x * EPB, e1 = min(e0 + EPB, N_EDGES);
    for (int e = e0 + tid; e < e1; e += 256) atomicAdd(&cnt[dst[e] >> 8], 1);
    __syncthreads();
    for (int i = tid; i < NBUCK; i += 256) {
        int v = cnt[i];
        base[i] = i * CAPB + (v ? atomicAdd(&gcur[i], v) : 0);
        cnt[i] = 0;
    }
    __syncthreads();
    for (int e = e0 + tid; e < e1; e += 256) {
        int d = dst[e], b = d >> 8;
        int r = atomicAdd(&cnt[b], 1);
        pairs[base[b] + r] = (unsigned)src[e] | ((unsigned)(d & 255) << 17);
    }
}

// ---------- pack W into MFMA B-fragment order ----------
// Bp[layer*2048 + (c*8+f)*64 + l] = W[(f*16+(l&15))*128 + c*32 + (l>>4)*8 + j]
__global__ __launch_bounds__(64) void pack_w(const float* __restrict__ W0,
                                             const float* __restrict__ W1,
                                             const float* __restrict__ W2,
                                             uint4* __restrict__ Bp) {
    int b = blockIdx.x;             // 0..95
    int layer = b >> 5;
    int r = b & 31;
    int c = r >> 3, f = r & 7;
    const float* W = (layer == 0) ? W0 : (layer == 1) ? W1 : W2;
    int l = threadIdx.x;
    int col = f * 16 + (l & 15);
    int k0 = c * 32 + (l >> 4) * 8;
    U16 o;
    #pragma unroll
    for (int j = 0; j < 8; ++j) o.h[j] = (_Float16)W[col * 128 + k0 + j];
    Bp[layer * 2048 + (c * 8 + f) * 64 + l] = o.u;
}

// ---------- scan: counts in gcur -> boff prefix; off[N]=E ----------
__global__ __launch_bounds__(512) void bucket_scan(const int* __restrict__ gcur,
                                                   int* __restrict__ boff,
                                                   int* __restrict__ off) {
    __shared__ int ws[8];
    int tid = threadIdx.x;
    int v = (tid < NBUCK) ? gcur[tid] : 0;
    int lane = tid & 63, w = tid >> 6;
    int incl = v;
    #pragma unroll
    for (int s = 1; s < 64; s <<= 1) { int y = __shfl_up(incl, s, 64); if (lane >= s) incl += y; }
    if (lane == 63) ws[w] = incl;
    __syncthreads();
    if (tid < 8) {
        int t = ws[tid];
        #pragma unroll
        for (int s = 1; s < 8; s <<= 1) { int y = __shfl_up(t, s, 64); if (tid >= s) t += y; }
        ws[tid] = t;
    }
    __syncthreads();
    int excl = (w ? ws[w - 1] : 0) + incl - v;
    if (tid < NBUCK) boff[tid] = excl;
    if (tid == NBUCK - 1) boff[NBUCK] = excl + v;
    if (tid == 0) off[N_NODES] = N_EDGES;
}

// ---------- fine sort within bucket -> off[] + srclist[] ----------
__global__ __launch_bounds__(256) void bucket_fine(const unsigned* __restrict__ pairs,
                                                   const int* __restrict__ boff,
                                                   int* __restrict__ off,
                                                   int* __restrict__ srclist) {
    __shared__ int ncnt[256];
    __shared__ int ws[4];
    __shared__ int stage[CAP];
    int tid = threadIdx.x, b = blockIdx.x;
    int eLo = boff[b], m = boff[b + 1] - eLo;
    int sb = b * CAPB;
    ncnt[tid] = 0;
    __syncthreads();
    for (int t = tid; t < m; t += 256) {
        unsigned p = pairs[sb + t];
        atomicAdd(&ncnt[(p >> 17) & 255], 1);
    }
    __syncthreads();
    int v = ncnt[tid];
    int lane = tid & 63, w = tid >> 6;
    int incl = v;
    #pragma unroll
    for (int s = 1; s < 64; s <<= 1) { int y = __shfl_up(incl, s, 64); if (lane >= s) incl += y; }
    if (lane == 63) ws[w] = incl;
    __syncthreads();
    if (tid < 4) {
        int t = ws[tid];
        #pragma unroll
        for (int s = 1; s < 4; s <<= 1) { int y = __shfl_up(t, s, 64); if (tid >= s) t += y; }
        ws[tid] = t;
    }
    __syncthreads();
    int excl = (w ? ws[w - 1] : 0) + incl - v;
    int n = (b << 8) + tid;
    if (n < N_NODES) off[n] = eLo + excl;
    __syncthreads();
    ncnt[tid] = excl;   // cursor
    __syncthreads();
    for (int t = tid; t < m; t += 256) {
        unsigned p = pairs[sb + t];
        int r = atomicAdd(&ncnt[(p >> 17) & 255], 1);
        int s = (int)(p & 0x1FFFFu);
        if (r < CAP) stage[r] = s;
        else srclist[eLo + r] = s;
    }
    __syncthreads();
    int lim = m < CAP ? m : CAP;
    for (int t = tid; t < lim; t += 256) srclist[eLo + t] = stage[t];
}

// ---------- pull aggregation: predicated batch-8 gathers, no scalar tail ----------
__global__ __launch_bounds__(256) void agg_f16(const uint4* __restrict__ Xh,
                                               uint4* __restrict__ Ah,
                                               const int* __restrict__ off,
                                               const int* __restrict__ srclist) {
    int t = blockIdx.x * 256 + threadIdx.x;
    int n = t >> 4, c = t & 15;
    if (n >= N_NODES) return;
    int j0 = off[n], j1 = off[n + 1];
    U16 acc; acc.u = Xh[(size_t)n * 16 + c];   // own row (GIN eps=0)
    half8 a = acc.h;
    for (int j = j0; j < j1; j += 8) {
        int idx[8]; unsigned msk[8];
        #pragma unroll
        for (int i = 0; i < 8; ++i) {
            int jj = j + i;
            bool ok = jj < j1;
            // srclist read is in-bounds scratch even when !ok (reads trailing ints);
            // index is replaced by own row n so the address is always valid.
            int s = srclist[jj];
            idx[i] = ok ? s : n;
            msk[i] = ok ? 0xFFFFFFFFu : 0u;
        }
        U16 v[8];
        #pragma unroll
        for (int i = 0; i < 8; ++i) v[i].u = Xh[(size_t)idx[i] * 16 + c];
        #pragma unroll
        for (int i = 0; i < 8; ++i) {
            v[i].u.x &= msk[i]; v[i].u.y &= msk[i];
            v[i].u.z &= msk[i]; v[i].u.w &= msk[i];
            a += v[i].h;
        }
    }
    U16 o; o.h = a;
    Ah[(size_t)n * 16 + c] = o.u;
}

// ---------- MFMA GEMM: H[n] = act(A[n] @ W.T + b), A-frags from global, no LDS ----------
__global__ __launch_bounds__(256) void gemm_mfma(const _Float16* __restrict__ Ah,
                                                 const uint4* __restrict__ Bp,
                                                 const float* __restrict__ bias,
                                                 _Float16* __restrict__ H, int doRelu) {
    int tid = threadIdx.x;
    int wid = tid >> 6, lane = tid & 63;
    int nbase = blockIdx.x * 128 + wid * 32;
    int lrow = lane & 15;
    int lk = (lane >> 4) * 8;
    int row0 = min(nbase + lrow, N_NODES - 1);
    int row1 = min(nbase + 16 + lrow, N_NODES - 1);

    floatx4 acc[2][8];
    #pragma unroll
    for (int r = 0; r < 2; ++r)
        #pragma unroll
        for (int f = 0; f < 8; ++f) acc[r][f] = (floatx4)0.f;

    #pragma unroll
    for (int c = 0; c < 4; ++c) {
        U16 a0, a1;
        a0.u = *(const uint4*)(Ah + (size_t)row0 * 128 + c * 32 + lk);
        a1.u = *(const uint4*)(Ah + (size_t)row1 * 128 + c * 32 + lk);
        #pragma unroll
        for (int f = 0; f < 8; ++f) {
            U16 b; b.u = Bp[(c * 8 + f) * 64 + lane];
            acc[0][f] = __builtin_amdgcn_mfma_f32_16x16x32_f16(a0.h, b.h, acc[0][f], 0, 0, 0);
            acc[1][f] = __builtin_amdgcn_mfma_f32_16x16x32_f16(a1.h, b.h, acc[1][f], 0, 0, 0);
        }
    }

    int colb = lane & 15;
    int rq = (lane >> 4) * 4;
    #pragma unroll
    for (int f = 0; f < 8; ++f) {
        float bv = bias[f * 16 + colb];
        #pragma unroll
        for (int r = 0; r < 2; ++r) {
            #pragma unroll
            for (int q = 0; q < 4; ++q) {
                int row = nbase + r * 16 + rq + q;
                if (row < N_NODES) {
                    float v = acc[r][f][q] + bv;
                    if (doRelu) v = fmaxf(v, 0.f);
                    H[(size_t)row * 128 + f * 16 + colb] = (_Float16)v;
                }
            }
        }
    }
}

// ---------- pooling + classifier ----------
__device__ __forceinline__ int lower_bound_i(const int* a, int n, int val) {
    int lo = 0, hi = n;
    while (lo < hi) {
        int mid = (lo + hi) >> 1;
        if (a[mid] < val) lo = mid + 1; else hi = mid;
    }
    return lo;
}

__global__ __launch_bounds__(256) void pool_kernel(const uint4* __restrict__ Hh,
                                                   const int* __restrict__ batch,
                                                   const float* __restrict__ Wg,
                                                   const float* __restrict__ bg,
                                                   float* __restrict__ out) {
    __shared__ float p[16 * 128];
    __shared__ float pooled[128];
    int g = blockIdx.x, tid = threadIdx.x;
    int c = tid & 15, r = tid >> 4;
    int lo = lower_bound_i(batch, N_NODES, g);
    int hi = lower_bound_i(batch, N_NODES, g + 1);
    float acc[8] = {0, 0, 0, 0, 0, 0, 0, 0};
    for (int i = lo + r; i < hi; i += 16) {
        U16 v; v.u = Hh[(size_t)i * 16 + c];
        #pragma unroll
        for (int k = 0; k < 8; ++k) acc[k] += (float)v.h[k];
    }
    #pragma unroll
    for (int k = 0; k < 8; ++k) p[r * 128 + c * 8 + k] = acc[k];
    __syncthreads();
    if (tid < 128) {
        float s = 0.f;
        #pragma unroll
        for (int q = 0; q < 16; ++q) s += p[q * 128 + tid];
        pooled[tid] = s / fmaxf((float)(hi - lo), 1.0f);
    }
    __syncthreads();
    if (tid < 10) {
        float s = bg[tid];
        #pragma unroll 4
        for (int k = 0; k < 128; ++k) s += pooled[k] * Wg[tid * 128 + k];
        out[g * 10 + tid] = s;
    }
}

// ---------- launch ----------
extern "C" void kernel_launch(void* const* d_in, const int* in_sizes, int n_in,
                              void* d_out, int out_size, void* d_ws, size_t ws_size,
                              hipStream_t stream) {
    const float* x   = (const float*)d_in[0];
    const int*   ei  = (const int*)d_in[1];
    const int*   bat = (const int*)d_in[2];
    const float* W0  = (const float*)d_in[3];
    const float* b0  = (const float*)d_in[4];
    const float* W1  = (const float*)d_in[5];
    const float* b1  = (const float*)d_in[6];
    const float* W2  = (const float*)d_in[7];
    const float* b2  = (const float*)d_in[8];
    const float* Wg  = (const float*)d_in[9];
    const float* bg  = (const float*)d_in[10];
    float* out = (float*)d_out;

    const int* src = ei;
    const int* dst = ei + N_EDGES;

    char* w = (char*)d_ws;
    _Float16* Ah    = (_Float16*)(w);               // 25.6 MB fp16 A (aliases pairs)
    unsigned* pairs = (unsigned*)(w);               // 7.6 MB, dead before first agg
    _Float16* P0    = (_Float16*)(w + 25600000);    // X mirror; later H2
    _Float16* P1    = (_Float16*)(w + 51200000);    // H0
    _Float16* P2    = (_Float16*)(w + 76800000);    // H1
    int*    srclist = (int*)(w + 102400000);        // 6.4 MB
    int*    off     = (int*)(w + 108800000);        // 400,016 B
    uint4*  Bp      = (uint4*)(w + 109300000);      // 98,304 B
    int*    gcur    = (int*)(w + 109450000);        // NBUCK ints
    int*    boff    = gcur + NBUCK + 1;             // NBUCK+1 ints

    hipMemsetAsync(gcur, 0, NBUCK * sizeof(int), stream);

    // CSR build + prep (separate dispatches; heterogeneous merge regressed in r6)
    bucket_scatter<<<NB_SCAT, 256, 0, stream>>>(src, dst, gcur, pairs);
    bucket_scan<<<1, 512, 0, stream>>>(gcur, boff, off);
    bucket_fine<<<NBUCK, 256, 0, stream>>>(pairs, boff, off, srclist);
    convert_f16<<<(N_NODES * 16 + 255) / 256, 256, 0, stream>>>((const float4*)x, (uint4*)P0);
    pack_w<<<96, 64, 0, stream>>>(W0, W1, W2, Bp);

    int aggGrid  = (N_NODES * 16 + 255) / 256;   // 6250
    int gemmGrid = (N_NODES + 127) / 128;        // 782

    // layer 0: P0 -> A -> P1
    agg_f16<<<aggGrid, 256, 0, stream>>>((const uint4*)P0, (uint4*)Ah, off, srclist);
    gemm_mfma<<<gemmGrid, 256, 0, stream>>>(Ah, Bp, b0, P1, 1);
    // layer 1: P1 -> A -> P2
    agg_f16<<<aggGrid, 256, 0, stream>>>((const uint4*)P1, (uint4*)Ah, off, srclist);
    gemm_mfma<<<gemmGrid, 256, 0, stream>>>(Ah, Bp + 2048, b1, P2, 1);
    // layer 2: P2 -> A -> P0
    agg_f16<<<aggGrid, 256, 0, stream>>>((const uint4*)P2, (uint4*)Ah, off, srclist);
    gemm_mfma<<<gemmGrid, 256, 0, stream>>>(Ah, Bp + 4096, b2, P0, 0);

    // pool + classifier
    pool_kernel<<<N_GRAPHS, 256, 0, stream>>>((const uint4*)P0, bat, Wg, bg, out);
}